// Round 3
// baseline (493.377 us; speedup 1.0000x reference)
//
#include <hip/hip_runtime.h>
#include <hip/hip_bf16.h>
#include <hip/hip_fp8.h>
#include <math.h>

typedef float f32x4 __attribute__((ext_vector_type(4)));

#define MTOT 16384
#define HALF 8192
#define KDIM 256                  /* bytes per row in fp8 Z */
#define BM 128
#define NB (MTOT / BM)            /* 128 block-rows */
#define NBLK (NB * (NB + 1) / 2)  /* 8256 upper-triangle blocks */

#define GLDS16(g, l) __builtin_amdgcn_global_load_lds(                      \
    (const __attribute__((address_space(1))) void*)(g),                     \
    (__attribute__((address_space(3))) void*)(l), 16, 0, 0)

// ---------------------------------------------------------------------------
// Pass 1: fp32 -> fp8 e4m3 (OCP) convert of stacked Z = [N; R]; per-row
// squared norms computed FROM THE QUANTIZED values so the diagonal of the
// kernel matrix cancels to d2 ~ 0 (exp = 1) despite fp8 MFMA.
// ---------------------------------------------------------------------------
__global__ __launch_bounds__(256) void convert_kernel(
    const float* __restrict__ Nmat, const float* __restrict__ Rmat,
    unsigned char* __restrict__ Z, float* __restrict__ x2) {
  const int lane = threadIdx.x & 63;
  const int wv = threadIdx.x >> 6;
  const int row = blockIdx.x * 4 + wv;          // 0..16383
  const float* src = (row < HALF) ? (Nmat + (size_t)row * KDIM)
                                  : (Rmat + (size_t)(row - HALF) * KDIM);
  float4 v = *(const float4*)(src + lane * 4);
  __hip_fp8_e4m3 q0(v.x), q1(v.y), q2(v.z), q3(v.w);
  uchar4 pk;
  pk.x = q0.__x; pk.y = q1.__x; pk.z = q2.__x; pk.w = q3.__x;
  *(uchar4*)(Z + (size_t)row * KDIM + lane * 4) = pk;
  float d0 = (float)q0, d1 = (float)q1, d2 = (float)q2, d3 = (float)q3;
  float sq = d0 * d0 + d1 * d1 + d2 * d2 + d3 * d3;
  #pragma unroll
  for (int off = 32; off; off >>= 1) sq += __shfl_down(sq, off);
  if (lane == 0) x2[row] = sq;
}

// ---------------------------------------------------------------------------
// Pass 2: upper-block-triangular S = Z Z^T (fp8 MFMA) with fused RBF +
// signed reduction. One-shot staging: the whole 128x256 A and B tiles land
// in LDS with 16 GLDS16 per wave -> ONE barrier per block, then 8 unbroken
// k-steps (64 ds_read_b64 + 128 MFMA), then shuffle-reduce + 1 atomic/wave.
//
// LDS swizzle: global 16B chunk c (0..15) of row r is placed at slot
// c ^ (r & 7). Read phases (16 lanes, fixed fq => fixed c) then hit
// 8 bank-pairs x 2 lanes = uniform 2-way = free (m136). The previous
// fr&3 key collided with the row-parity bank bit -> 4-way (25M conflicts).
// ---------------------------------------------------------------------------
__global__ __launch_bounds__(256) void mmd_gemm(
    const unsigned char* __restrict__ Z, const float* __restrict__ x2,
    float* __restrict__ accum) {
  // Closed-form decode of linear block id -> (bm, bn), bn >= bm.
  const int t = blockIdx.x;
  const int u = NBLK - 1 - t;
  int rr = (int)((sqrtf(8.0f * (float)u + 1.0f) - 1.0f) * 0.5f);
  while (rr * (rr + 1) / 2 > u) --rr;
  while ((rr + 1) * (rr + 2) / 2 <= u) ++rr;
  const int bm = NB - 1 - rr;
  const int bn = bm + (t - (bm * NB - bm * (bm - 1) / 2));

  __shared__ unsigned char As[BM * KDIM];   // 32 KB
  __shared__ unsigned char Bs[BM * KDIM];   // 32 KB

  const int tid  = threadIdx.x;
  const int lane = tid & 63;
  const int wid  = tid >> 6;       // 0..3
  const int wm   = wid >> 1;       // wave row (0..1)
  const int wn   = wid & 1;        // wave col (0..1)

  const unsigned char* Abase = Z + (size_t)bm * BM * KDIM;
  const unsigned char* Bbase = Z + (size_t)bn * BM * KDIM;

  // Staging: instruction i (0..31) fills rows 4i..4i+3 (64 chunks = 1 KB).
  // lane -> local row lr = lane>>4, slot ls = lane&15; slot ls of row gr
  // receives global chunk ls ^ (gr&7).
  {
    const int lr = lane >> 4;
    const int ls = lane & 15;
    #pragma unroll
    for (int tt = 0; tt < 8; ++tt) {
      int i = wid * 8 + tt;                 // wave-uniform instruction id
      int gr = i * 4 + lr;                  // tile row 0..127
      int c = ls ^ (gr & 7);
      GLDS16(Abase + (size_t)gr * KDIM + c * 16, As + i * 1024);
      GLDS16(Bbase + (size_t)gr * KDIM + c * 16, Bs + i * 1024);
    }
  }
  __syncthreads();   // the ONLY barrier: drains GLDS vmcnt, all tiles ready

  // Fragment geometry (16x16x32 fp8): lane (fr, fq) needs row-bytes
  // [ks*32 + fq*8, +8) => global chunk c = 2*ks + (fq>>1), byte (fq&1)*8.
  const int fr = lane & 15;
  const int fq = lane >> 4;        // 0..3
  const int fh = fq >> 1;
  const int fl = (fq & 1) * 8;

  f32x4 zero = {0.f, 0.f, 0.f, 0.f};
  f32x4 acc[4][4];
  #pragma unroll
  for (int i = 0; i < 4; ++i)
    #pragma unroll
    for (int j = 0; j < 4; ++j) acc[i][j] = zero;

  #pragma unroll
  for (int ks = 0; ks < 8; ++ks) {
    long long af[4], bfg[4];
    #pragma unroll
    for (int tm = 0; tm < 4; ++tm) {
      int row = wm * 64 + tm * 16 + fr;
      int off = row * KDIM + (((2 * ks + fh) ^ (row & 7)) * 16) + fl;
      af[tm] = *(const long long*)(As + off);
    }
    #pragma unroll
    for (int tn = 0; tn < 4; ++tn) {
      int row = wn * 64 + tn * 16 + fr;
      int off = row * KDIM + (((2 * ks + fh) ^ (row & 7)) * 16) + fl;
      bfg[tn] = *(const long long*)(Bs + off);
    }
    #pragma unroll
    for (int tm = 0; tm < 4; ++tm)
      #pragma unroll
      for (int tn = 0; tn < 4; ++tn)
        acc[tm][tn] = __builtin_amdgcn_mfma_f32_16x16x32_fp8_fp8(
            af[tm], bfg[tn], acc[tm][tn], 0, 0, 0);
  }

  // Epilogue: d2 = x2[i]+x2[j]-2s, clamp, exp, signed sum.
  float partial = 0.f;
  #pragma unroll
  for (int tm = 0; tm < 4; ++tm) {
    #pragma unroll
    for (int tn = 0; tn < 4; ++tn) {
      int col_g = bn * BM + wn * 64 + tn * 16 + fr;
      float x2c = x2[col_g];
      #pragma unroll
      for (int v = 0; v < 4; ++v) {
        int row_g = bm * BM + wm * 64 + tm * 16 + fq * 4 + v;
        float s = acc[tm][tn][v];
        float d2 = x2[row_g] + x2c - 2.f * s;
        d2 = fmaxf(d2, 0.f);
        partial += __expf(-d2);
      }
    }
  }

  // Block weight: sign(N/R half); off-diag blocks x2 (symmetry). Row 8192
  // boundary == block 64, so sign is block-uniform.
  float wgt = ((bm < NB / 2) == (bn < NB / 2)) ? 1.f : -1.f;
  if (bm != bn) wgt *= 2.f;

  #pragma unroll
  for (int off = 32; off; off >>= 1) partial += __shfl_down(partial, off);
  if (lane == 0) atomicAdd(accum, partial * wgt);   // 4 atomics/block
}

__global__ void finalize_kernel(const float* __restrict__ accum,
                                float* __restrict__ out) {
  if (threadIdx.x == 0 && blockIdx.x == 0) {
    float mmd = accum[0] / ((float)HALF * (float)HALF);
    out[0] = sqrtf(fmaxf(mmd, 0.f));
  }
}

extern "C" void kernel_launch(void* const* d_in, const int* in_sizes, int n_in,
                              void* d_out, int out_size, void* d_ws, size_t ws_size,
                              hipStream_t stream) {
  const float* Nmat = (const float*)d_in[0];
  const float* Rmat = (const float*)d_in[1];
  float* out = (float*)d_out;

  char* ws = (char*)d_ws;
  unsigned char* Z = (unsigned char*)ws;                     // 16384*256 = 4 MiB
  float* x2    = (float*)(ws + (size_t)MTOT * KDIM);         // 64 KiB
  float* accum = (float*)(ws + (size_t)MTOT * KDIM + MTOT * 4);

  hipMemsetAsync(accum, 0, sizeof(float), stream);
  convert_kernel<<<MTOT / 4, 256, 0, stream>>>(Nmat, Rmat, Z, x2);
  mmd_gemm<<<NBLK, 256, 0, stream>>>(Z, x2, accum);
  finalize_kernel<<<1, 64, 0, stream>>>(accum, out);
}

// Round 4
// 147.733 us; speedup vs baseline: 3.3396x; 3.3396x over previous
//
#include <hip/hip_runtime.h>
#include <hip/hip_bf16.h>
#include <hip/hip_fp8.h>
#include <math.h>

typedef float f32x4 __attribute__((ext_vector_type(4)));

#define MTOT 16384
#define HALF 8192
#define KDIM 256                  /* bytes per row in fp8 Z */
#define BM 128
#define NB (MTOT / BM)            /* 128 block-rows */
#define NBLK (NB * (NB + 1) / 2)  /* 8256 upper-triangle blocks */
#define NPART (NBLK * 4)          /* one partial per wave */

#define GLDS16(g, l) __builtin_amdgcn_global_load_lds(                      \
    (const __attribute__((address_space(1))) void*)(g),                     \
    (__attribute__((address_space(3))) void*)(l), 16, 0, 0)

// ---------------------------------------------------------------------------
// Pass 1: fp32 -> fp8 e4m3 (OCP) convert of stacked Z = [N; R]; per-row
// squared norms computed FROM THE QUANTIZED values so the diagonal of the
// kernel matrix cancels to d2 ~ 0 (exp = 1) despite fp8 MFMA.
// ---------------------------------------------------------------------------
__global__ __launch_bounds__(256) void convert_kernel(
    const float* __restrict__ Nmat, const float* __restrict__ Rmat,
    unsigned char* __restrict__ Z, float* __restrict__ x2) {
  const int lane = threadIdx.x & 63;
  const int wv = threadIdx.x >> 6;
  const int row = blockIdx.x * 4 + wv;          // 0..16383
  const float* src = (row < HALF) ? (Nmat + (size_t)row * KDIM)
                                  : (Rmat + (size_t)(row - HALF) * KDIM);
  float4 v = *(const float4*)(src + lane * 4);
  __hip_fp8_e4m3 q0(v.x), q1(v.y), q2(v.z), q3(v.w);
  uchar4 pk;
  pk.x = q0.__x; pk.y = q1.__x; pk.z = q2.__x; pk.w = q3.__x;
  *(uchar4*)(Z + (size_t)row * KDIM + lane * 4) = pk;
  float d0 = (float)q0, d1 = (float)q1, d2 = (float)q2, d3 = (float)q3;
  float sq = d0 * d0 + d1 * d1 + d2 * d2 + d3 * d3;
  #pragma unroll
  for (int off = 32; off; off >>= 1) sq += __shfl_down(sq, off);
  if (lane == 0) x2[row] = sq;
}

// ---------------------------------------------------------------------------
// Pass 2: upper-block-triangular S = Z Z^T (fp8 MFMA) with fused RBF +
// signed reduction. One-shot staging: whole 128x256 A and B tiles land in
// LDS (16 GLDS16/wave) -> ONE barrier per block, then 8 unbroken k-steps
// (64 ds_read_b64 + 128 MFMA per wave), epilogue exp + shuffle-reduce.
//
// Result handoff: NO same-address atomics (round-3 lesson: 33k same-line
// atomicAdds serialize at ~13 ns each at the owning TCC = 428 us kernel).
// Each wave plain-stores its weighted partial to a distinct slot; a tiny
// final kernel reduces 33k floats.
// ---------------------------------------------------------------------------
__global__ __launch_bounds__(256) void mmd_gemm(
    const unsigned char* __restrict__ Z, const float* __restrict__ x2,
    float* __restrict__ partials) {
  // Closed-form decode of linear block id -> (bm, bn), bn >= bm.
  const int t = blockIdx.x;
  const int u = NBLK - 1 - t;
  int rr = (int)((sqrtf(8.0f * (float)u + 1.0f) - 1.0f) * 0.5f);
  while (rr * (rr + 1) / 2 > u) --rr;
  while ((rr + 1) * (rr + 2) / 2 <= u) ++rr;
  const int bm = NB - 1 - rr;
  const int bn = bm + (t - (bm * NB - bm * (bm - 1) / 2));

  __shared__ unsigned char As[BM * KDIM];   // 32 KB
  __shared__ unsigned char Bs[BM * KDIM];   // 32 KB

  const int tid  = threadIdx.x;
  const int lane = tid & 63;
  const int wid  = tid >> 6;       // 0..3
  const int wm   = wid >> 1;       // wave row (0..1)
  const int wn   = wid & 1;        // wave col (0..1)

  const unsigned char* Abase = Z + (size_t)bm * BM * KDIM;
  const unsigned char* Bbase = Z + (size_t)bn * BM * KDIM;

  // Staging: instruction i (0..31) fills rows 4i..4i+3 (64 chunks = 1 KB).
  // Slot ls of row gr receives global 16B chunk ls ^ (gr&7)  (bank swizzle).
  {
    const int lr = lane >> 4;
    const int ls = lane & 15;
    #pragma unroll
    for (int tt = 0; tt < 8; ++tt) {
      int i = wid * 8 + tt;                 // wave-uniform instruction id
      int gr = i * 4 + lr;                  // tile row 0..127
      int c = ls ^ (gr & 7);
      GLDS16(Abase + (size_t)gr * KDIM + c * 16, As + i * 1024);
      GLDS16(Bbase + (size_t)gr * KDIM + c * 16, Bs + i * 1024);
    }
  }
  __syncthreads();   // the ONLY barrier: drains GLDS vmcnt, all tiles ready

  // Fragment geometry (16x16x32 fp8): lane (fr, fq) needs row-bytes
  // [ks*32 + fq*8, +8) => global chunk c = 2*ks + (fq>>1), byte (fq&1)*8.
  const int fr = lane & 15;
  const int fq = lane >> 4;        // 0..3
  const int fh = fq >> 1;
  const int fl = (fq & 1) * 8;

  f32x4 zero = {0.f, 0.f, 0.f, 0.f};
  f32x4 acc[4][4];
  #pragma unroll
  for (int i = 0; i < 4; ++i)
    #pragma unroll
    for (int j = 0; j < 4; ++j) acc[i][j] = zero;

  #pragma unroll
  for (int ks = 0; ks < 8; ++ks) {
    long long af[4], bfg[4];
    #pragma unroll
    for (int tm = 0; tm < 4; ++tm) {
      int row = wm * 64 + tm * 16 + fr;
      int off = row * KDIM + (((2 * ks + fh) ^ (row & 7)) * 16) + fl;
      af[tm] = *(const long long*)(As + off);
    }
    #pragma unroll
    for (int tn = 0; tn < 4; ++tn) {
      int row = wn * 64 + tn * 16 + fr;
      int off = row * KDIM + (((2 * ks + fh) ^ (row & 7)) * 16) + fl;
      bfg[tn] = *(const long long*)(Bs + off);
    }
    #pragma unroll
    for (int tm = 0; tm < 4; ++tm)
      #pragma unroll
      for (int tn = 0; tn < 4; ++tn)
        acc[tm][tn] = __builtin_amdgcn_mfma_f32_16x16x32_fp8_fp8(
            af[tm], bfg[tn], acc[tm][tn], 0, 0, 0);
  }

  // Epilogue: d2 = x2[i]+x2[j]-2s, clamp, exp, signed sum.
  float partial = 0.f;
  #pragma unroll
  for (int tm = 0; tm < 4; ++tm) {
    #pragma unroll
    for (int tn = 0; tn < 4; ++tn) {
      int col_g = bn * BM + wn * 64 + tn * 16 + fr;
      float x2c = x2[col_g];
      #pragma unroll
      for (int v = 0; v < 4; ++v) {
        int row_g = bm * BM + wm * 64 + tm * 16 + fq * 4 + v;
        float s = acc[tm][tn][v];
        float d2 = x2[row_g] + x2c - 2.f * s;
        d2 = fmaxf(d2, 0.f);
        partial += __expf(-d2);
      }
    }
  }

  // Block weight: sign(N/R half); off-diag blocks x2 (symmetry). Row 8192
  // boundary == block 64, so sign is block-uniform.
  float wgt = ((bm < NB / 2) == (bn < NB / 2)) ? 1.f : -1.f;
  if (bm != bn) wgt *= 2.f;

  #pragma unroll
  for (int off = 32; off; off >>= 1) partial += __shfl_down(partial, off);
  if (lane == 0) partials[blockIdx.x * 4 + wid] = partial * wgt;
}

// ---------------------------------------------------------------------------
// Pass 3: reduce the 33k per-wave partials, sqrt, store the scalar.
// ---------------------------------------------------------------------------
__global__ __launch_bounds__(1024) void finalize_kernel(
    const float* __restrict__ partials, float* __restrict__ out) {
  float s = 0.f;
  for (int i = threadIdx.x; i < NPART; i += 1024) s += partials[i];
  #pragma unroll
  for (int off = 32; off; off >>= 1) s += __shfl_down(s, off);
  __shared__ float ws[16];
  if ((threadIdx.x & 63) == 0) ws[threadIdx.x >> 6] = s;
  __syncthreads();
  if (threadIdx.x == 0) {
    float tot = 0.f;
    #pragma unroll
    for (int i = 0; i < 16; ++i) tot += ws[i];
    float mmd = tot / ((float)HALF * (float)HALF);
    out[0] = sqrtf(fmaxf(mmd, 0.f));
  }
}

extern "C" void kernel_launch(void* const* d_in, const int* in_sizes, int n_in,
                              void* d_out, int out_size, void* d_ws, size_t ws_size,
                              hipStream_t stream) {
  const float* Nmat = (const float*)d_in[0];
  const float* Rmat = (const float*)d_in[1];
  float* out = (float*)d_out;

  char* ws = (char*)d_ws;
  unsigned char* Z = (unsigned char*)ws;                     // 16384*256 = 4 MiB
  float* x2       = (float*)(ws + (size_t)MTOT * KDIM);      // 64 KiB
  float* partials = (float*)(ws + (size_t)MTOT * KDIM + MTOT * 4);  // 132 KiB

  convert_kernel<<<MTOT / 4, 256, 0, stream>>>(Nmat, Rmat, Z, x2);
  mmd_gemm<<<NBLK, 256, 0, stream>>>(Z, x2, partials);
  finalize_kernel<<<1, 1024, 0, stream>>>(partials, out);
}

// Round 5
// 121.024 us; speedup vs baseline: 4.0767x; 1.2207x over previous
//
#include <hip/hip_runtime.h>
#include <hip/hip_bf16.h>
#include <math.h>

typedef float f32x4 __attribute__((ext_vector_type(4)));
typedef int   i32x4 __attribute__((ext_vector_type(4)));
typedef int   i32x8 __attribute__((ext_vector_type(8)));
typedef float f32x2 __attribute__((ext_vector_type(2)));

#define MTOT 16384
#define HALF 8192
#define KDIM 256                  /* bytes per row in fp8 Z */
#define BM 128
#define NB (MTOT / BM)            /* 128 block-rows */
#define NBLK (NB * (NB + 1) / 2)  /* 8256 upper-triangle blocks */
#define NPART (NBLK * 4)          /* one partial per wave */

#define GLDS16(g, l) __builtin_amdgcn_global_load_lds(                      \
    (const __attribute__((address_space(1))) void*)(g),                     \
    (__attribute__((address_space(3))) void*)(l), 16, 0, 0)

// ---------------------------------------------------------------------------
// Pass 1: fp32 -> fp8 e4m3 (OCP) via HW v_cvt_pk_fp8_f32; per-row squared
// norms computed FROM THE QUANTIZED values (HW unpack) so the diagonal of
// the kernel matrix cancels to d2 ~ 0 regardless of quantization error.
// ---------------------------------------------------------------------------
__global__ __launch_bounds__(256) void convert_kernel(
    const float* __restrict__ Nmat, const float* __restrict__ Rmat,
    unsigned int* __restrict__ Z, float* __restrict__ x2) {
  const int lane = threadIdx.x & 63;
  const int wv = threadIdx.x >> 6;
  const int row = blockIdx.x * 4 + wv;          // 0..16383
  const float* src = (row < HALF) ? (Nmat + (size_t)row * KDIM)
                                  : (Rmat + (size_t)(row - HALF) * KDIM);
  float4 v = *(const float4*)(src + lane * 4);
  int pk = __builtin_amdgcn_cvt_pk_fp8_f32(v.x, v.y, 0, false);
  pk = __builtin_amdgcn_cvt_pk_fp8_f32(v.z, v.w, pk, true);
  Z[(size_t)row * (KDIM / 4) + lane] = (unsigned int)pk;
  f32x2 d01 = __builtin_amdgcn_cvt_pk_f32_fp8(pk, false);
  f32x2 d23 = __builtin_amdgcn_cvt_pk_f32_fp8(pk, true);
  float sq = d01[0] * d01[0] + d01[1] * d01[1] + d23[0] * d23[0] + d23[1] * d23[1];
  #pragma unroll
  for (int off = 32; off; off >>= 1) sq += __shfl_down(sq, off);
  if (lane == 0) x2[row] = sq;
}

// ---------------------------------------------------------------------------
// Pass 2: upper-block-triangular S = Z Z^T via MX-fp8 MFMA (16x16x128
// f8f6f4, unit E8M0 scales 0x7F = 1.0 -> plain fp8 GEMM at 2x rate).
//
// acc is INITIALIZED to -(x2[i]+x2[j])/2, so after the GEMM each element
// holds -d2/2 directly. Off-diagonal blocks (8128/8256) then need only a
// 64-wide max + __any(amax > -40) to prove every exp(-d2) rounds to 0 in
// fp32 (d2 ~ 512 for 256-dim Gaussians); the exp path runs only on the
// 128 diagonal blocks (and on any freak near pair - checked, not assumed).
//
// One-shot staging (64 KB LDS, one barrier); fragment reads are b128 with
// chunk-XOR swizzle: an 8-lane phase hits 8 distinct 16B slots = all 32
// banks -> conflict-free (round-4's b64 had 2 lanes/bank-pair in a 16-lane
// phase = +4 cyc/read).
// ---------------------------------------------------------------------------
__global__ __launch_bounds__(256, 2) void mmd_gemm(
    const unsigned char* __restrict__ Z, const float* __restrict__ x2,
    float* __restrict__ partials) {
  // Closed-form decode of linear block id -> (bm, bn), bn >= bm.
  const int t = blockIdx.x;
  const int u = NBLK - 1 - t;
  int rr = (int)((sqrtf(8.0f * (float)u + 1.0f) - 1.0f) * 0.5f);
  while (rr * (rr + 1) / 2 > u) --rr;
  while ((rr + 1) * (rr + 2) / 2 <= u) ++rr;
  const int bm = NB - 1 - rr;
  const int bn = bm + (t - (bm * NB - bm * (bm - 1) / 2));

  __shared__ unsigned char As[BM * KDIM];   // 32 KB
  __shared__ unsigned char Bs[BM * KDIM];   // 32 KB

  const int tid  = threadIdx.x;
  const int lane = tid & 63;
  const int wid  = tid >> 6;       // 0..3
  const int wm   = wid >> 1;       // wave row (0..1)
  const int wn   = wid & 1;        // wave col (0..1)

  const unsigned char* Abase = Z + (size_t)bm * BM * KDIM;
  const unsigned char* Bbase = Z + (size_t)bn * BM * KDIM;

  // Staging: instruction i (0..31) fills rows 4i..4i+3 (64 chunks = 1 KB).
  // Slot ls of row gr receives global 16B chunk ls ^ (gr&7)  (bank swizzle).
  {
    const int lr = lane >> 4;
    const int ls = lane & 15;
    #pragma unroll
    for (int tt = 0; tt < 8; ++tt) {
      int i = wid * 8 + tt;                 // wave-uniform instruction id
      int gr = i * 4 + lr;                  // tile row 0..127
      int c = ls ^ (gr & 7);
      GLDS16(Abase + (size_t)gr * KDIM + c * 16, As + i * 1024);
      GLDS16(Bbase + (size_t)gr * KDIM + c * 16, Bs + i * 1024);
    }
  }

  // While GLDS is in flight: fragment geometry + x2 loads + acc init.
  const int fr = lane & 15;
  const int fq = lane >> 4;        // 0..3

  float xrh[4][4], xch[4];         // -x2/2 for my rows / cols
  #pragma unroll
  for (int tm = 0; tm < 4; ++tm)
    #pragma unroll
    for (int v = 0; v < 4; ++v)
      xrh[tm][v] = -0.5f * x2[bm * BM + wm * 64 + tm * 16 + fq * 4 + v];
  #pragma unroll
  for (int tn = 0; tn < 4; ++tn)
    xch[tn] = -0.5f * x2[bn * BM + wn * 64 + tn * 16 + fr];

  f32x4 acc[4][4];
  #pragma unroll
  for (int tm = 0; tm < 4; ++tm)
    #pragma unroll
    for (int tn = 0; tn < 4; ++tn)
      #pragma unroll
      for (int v = 0; v < 4; ++v)
        acc[tm][tn][v] = xrh[tm][v] + xch[tn];

  __syncthreads();   // the ONLY barrier: drains GLDS vmcnt, tiles ready

  // Fragment reads: lane (fr,fq), k-slab ks (0/1) needs row-bytes
  // [ks*128 + fq*32, +32) = global chunks c0 = ks*8+fq*2, c0+1, each at
  // LDS slot c ^ (row&7); row&7 == fr&7.
  const int key = fr & 7;
  #pragma unroll
  for (int ks = 0; ks < 2; ++ks) {
    const int c0 = ks * 8 + fq * 2;
    i32x8 af[4], bf[4];
    #pragma unroll
    for (int tm = 0; tm < 4; ++tm) {
      int row = wm * 64 + tm * 16 + fr;
      i32x4 lo = *(const i32x4*)(As + row * KDIM + ((c0 ^ key) * 16));
      i32x4 hi = *(const i32x4*)(As + row * KDIM + (((c0 + 1) ^ key) * 16));
      af[tm] = __builtin_shufflevector(lo, hi, 0, 1, 2, 3, 4, 5, 6, 7);
    }
    #pragma unroll
    for (int tn = 0; tn < 4; ++tn) {
      int row = wn * 64 + tn * 16 + fr;
      i32x4 lo = *(const i32x4*)(Bs + row * KDIM + ((c0 ^ key) * 16));
      i32x4 hi = *(const i32x4*)(Bs + row * KDIM + (((c0 + 1) ^ key) * 16));
      bf[tn] = __builtin_shufflevector(lo, hi, 0, 1, 2, 3, 4, 5, 6, 7);
    }
    #pragma unroll
    for (int tm = 0; tm < 4; ++tm)
      #pragma unroll
      for (int tn = 0; tn < 4; ++tn)
        acc[tm][tn] = __builtin_amdgcn_mfma_scale_f32_16x16x128_f8f6f4(
            af[tm], bf[tn], acc[tm][tn], 0, 0,
            0, 0x7F7F7F7F, 0, 0x7F7F7F7F);
  }

  // Epilogue. acc = -d2/2. exp(-d2) == 0 in fp32 whenever acc <= -40
  // (e^-80 summed over all pairs is ~1e-26, vs error budget ~6e2).
  float amax = -1e30f;
  #pragma unroll
  for (int tm = 0; tm < 4; ++tm)
    #pragma unroll
    for (int tn = 0; tn < 4; ++tn)
      #pragma unroll
      for (int v = 0; v < 4; ++v)
        amax = fmaxf(amax, acc[tm][tn][v]);

  float partial = 0.f;
  if (__any(amax > -40.f)) {       // diagonal blocks + any freak near-pair
    #pragma unroll
    for (int tm = 0; tm < 4; ++tm)
      #pragma unroll
      for (int tn = 0; tn < 4; ++tn)
        #pragma unroll
        for (int v = 0; v < 4; ++v) {
          float a = fminf(acc[tm][tn][v], 0.f);   // clamp d2 >= 0
          partial += exp2f(a * 2.885390082f);     // exp(2a)
        }
  }

  // Block weight: sign(N/R half); off-diag blocks x2 (symmetry). Row 8192
  // boundary == block 64, so sign is block-uniform.
  float wgt = ((bm < NB / 2) == (bn < NB / 2)) ? 1.f : -1.f;
  if (bm != bn) wgt *= 2.f;

  #pragma unroll
  for (int off = 32; off; off >>= 1) partial += __shfl_down(partial, off);
  if (lane == 0) partials[blockIdx.x * 4 + wid] = partial * wgt;
}

// ---------------------------------------------------------------------------
// Pass 3: reduce the 33k per-wave partials, sqrt, store the scalar.
// ---------------------------------------------------------------------------
__global__ __launch_bounds__(1024) void finalize_kernel(
    const float* __restrict__ partials, float* __restrict__ out) {
  float s = 0.f;
  for (int i = threadIdx.x; i < NPART; i += 1024) s += partials[i];
  #pragma unroll
  for (int off = 32; off; off >>= 1) s += __shfl_down(s, off);
  __shared__ float ws[16];
  if ((threadIdx.x & 63) == 0) ws[threadIdx.x >> 6] = s;
  __syncthreads();
  if (threadIdx.x == 0) {
    float tot = 0.f;
    #pragma unroll
    for (int i = 0; i < 16; ++i) tot += ws[i];
    float mmd = tot / ((float)HALF * (float)HALF);
    out[0] = sqrtf(fmaxf(mmd, 0.f));
  }
}

extern "C" void kernel_launch(void* const* d_in, const int* in_sizes, int n_in,
                              void* d_out, int out_size, void* d_ws, size_t ws_size,
                              hipStream_t stream) {
  const float* Nmat = (const float*)d_in[0];
  const float* Rmat = (const float*)d_in[1];
  float* out = (float*)d_out;

  char* ws = (char*)d_ws;
  unsigned char* Z = (unsigned char*)ws;                     // 16384*256 = 4 MiB
  float* x2       = (float*)(ws + (size_t)MTOT * KDIM);      // 64 KiB
  float* partials = (float*)(ws + (size_t)MTOT * KDIM + MTOT * 4);  // 132 KiB

  convert_kernel<<<MTOT / 4, 256, 0, stream>>>(Nmat, Rmat, (unsigned int*)Z, x2);
  mmd_gemm<<<NBLK, 256, 0, stream>>>(Z, x2, partials);
  finalize_kernel<<<1, 1024, 0, stream>>>(partials, out);
}